// Round 1
// baseline (1950.109 us; speedup 1.0000x reference)
//
#include <hip/hip_runtime.h>
#include <hip/hip_bf16.h>
#include <math.h>

#define NTOK   288      // B*L
#define NV     3
#define NTV    864      // NV*NTOK
#define NSEL   3456     // NTV*4
#define DMODEL 512
#define NEXP   16
#define TOPK   4
#define NHEAD  8
#define DHEAD  64
#define HFF    2048     // 4*D (experts), also ffn hidden
#define RESN   5000

__device__ __forceinline__ float gelu_exact(float x) {
    return 0.5f * x * (1.0f + erff(x * 0.70710678118654752f));
}

// ---------------- K0: views + router + top-k ----------------
__global__ __launch_bounds__(256) void build_tokens(
    const int* __restrict__ Z,
    const float* __restrict__ emb0, const float* __restrict__ p0w, const float* __restrict__ p0b,
    const float* __restrict__ emb1, const float* __restrict__ p1w, const float* __restrict__ p1b,
    const float* __restrict__ emb2, const float* __restrict__ p2w, const float* __restrict__ p2b,
    const float* __restrict__ keys, const float* __restrict__ router_w, const float* __restrict__ router_b,
    float* __restrict__ v_out, float* __restrict__ w4, int* __restrict__ idx4)
{
    int tv = blockIdx.x;
    int vi = tv / NTOK, t = tv % NTOK;
    int tid = threadIdx.x;

    const float* emb; const float* pw; const float* pb; int F;
    if (vi == 0)      { emb = emb0; pw = p0w; pb = p0b; F = 200; }
    else if (vi == 1) { emb = emb1; pw = p1w; pb = p1b; F = 132; }
    else              { emb = emb2; pw = p2w; pb = p2b; F = 112; }
    const float* rw = router_w + (size_t)vi * DMODEL * NEXP;
    const float* rb = router_b + vi * NEXP;

    __shared__ float er[200];
    __shared__ float vs[DMODEL];
    __shared__ float red[256];
    __shared__ float logits[NEXP];
    __shared__ float vsq_s;

    int z = Z[t];
    for (int f = tid; f < F; f += 256) er[f] = emb[(size_t)z * F + f];
    __syncthreads();

    float a0 = pb[tid], a1 = pb[tid + 256];
    for (int f = 0; f < F; ++f) {
        float e = er[f];
        a0 += e * pw[f * DMODEL + tid];
        a1 += e * pw[f * DMODEL + tid + 256];
    }
    vs[tid] = a0; vs[tid + 256] = a1;
    v_out[(size_t)tv * DMODEL + tid] = a0;
    v_out[(size_t)tv * DMODEL + tid + 256] = a1;

    red[tid] = a0 * a0 + a1 * a1;
    __syncthreads();
    for (int s = 128; s > 0; s >>= 1) { if (tid < s) red[tid] += red[tid + s]; __syncthreads(); }
    if (tid == 0) vsq_s = red[0];
    __syncthreads();
    float vsq = vsq_s;

    // each wave handles 4 experts: logit = -vsq - sum(k*(k-2v)) + sum(v*rw) + rb
    int lane = tid & 63, wv = tid >> 6;
    for (int ei = 0; ei < 4; ++ei) {
        int e = wv * 4 + ei;
        float p = 0.0f;
        for (int d = lane; d < DMODEL; d += 64) {
            float vvv = vs[d];
            float kk = keys[e * DMODEL + d];
            p += vvv * rw[d * NEXP + e] - kk * (kk - 2.0f * vvv);
        }
        for (int off = 32; off > 0; off >>= 1) p += __shfl_down(p, off, 64);
        if (lane == 0) logits[e] = -vsq + p + rb[e];
    }
    __syncthreads();

    if (tid == 0) {
        float lv[NEXP];
        for (int e = 0; e < NEXP; ++e) lv[e] = logits[e];
        bool used[NEXP] = {false};
        int   tk[TOPK]; float tval[TOPK];
        for (int k = 0; k < TOPK; ++k) {
            int best = -1; float bv = -1e30f;
            for (int e = 0; e < NEXP; ++e)
                if (!used[e] && lv[e] > bv) { bv = lv[e]; best = e; }
            used[best] = true; tk[k] = best; tval[k] = bv;
        }
        float m = tval[0], sum = 0.0f, ww[TOPK];
        for (int k = 0; k < TOPK; ++k) { ww[k] = expf(tval[k] - m); sum += ww[k]; }
        for (int k = 0; k < TOPK; ++k) {
            w4[tv * TOPK + k] = ww[k] / sum;
            idx4[tv * TOPK + k] = tk[k];
        }
    }
}

// ---------------- K1: compact rows per expert ----------------
__global__ __launch_bounds__(256) void route_kernel(
    const int* __restrict__ idx4, int* __restrict__ offs,
    int* __restrict__ rows_tv, int* __restrict__ rows_s)
{
    __shared__ int cnt[NEXP], cur[NEXP], offsh[NEXP + 1];
    int tid = threadIdx.x;
    if (tid < NEXP) cnt[tid] = 0;
    __syncthreads();
    for (int s = tid; s < NSEL; s += 256) atomicAdd(&cnt[idx4[s]], 1);
    __syncthreads();
    if (tid == 0) {
        int o = 0;
        for (int e = 0; e < NEXP; ++e) { offsh[e] = o; o += cnt[e]; }
        offsh[NEXP] = o;
    }
    __syncthreads();
    if (tid < NEXP) cur[tid] = offsh[tid];
    if (tid <= NEXP) offs[tid] = offsh[tid];
    __syncthreads();
    for (int s = tid; s < NSEL; s += 256) {
        int e = idx4[s];
        int pos = atomicAdd(&cur[e], 1);
        rows_tv[pos] = s >> 2;
        rows_s[pos]  = s;
    }
}

// ---------------- MoE expert GEMM (64x64 tile, fp32) ----------------
// phase 1: A = v (rows via rows_tv), W = exp_w1[e], C = h[off+m], act = gelu, K=512,N=2048
// phase 2: A = h (rows off+m),       W = exp_w2[e], C = y_all[rows_s[off+m]], K=2048,N=512
__global__ __launch_bounds__(256) void gemm_moe(
    const float* __restrict__ Abase, const int* __restrict__ rows_tv,
    const int* __restrict__ rows_s, const int* __restrict__ offs,
    const float* __restrict__ Wbase, const float* __restrict__ Bbase,
    float* __restrict__ Cbase, int N, int K, int phase)
{
    int e  = blockIdx.y;
    int n0 = blockIdx.x * 64;
    int off = offs[e], cnt = offs[e + 1] - off;
    const float* W    = Wbase + (size_t)e * K * N;
    const float* bias = Bbase + (size_t)e * N;

    __shared__ float As[16][64];
    __shared__ float Ws[16][64];
    int tid = threadIdx.x;
    int tx = tid & 15, ty = tid >> 4;
    int arow = tid >> 2, ac4 = (tid & 3) * 4;
    int wrow = tid >> 4, wc4 = (tid & 15) * 4;

    for (int mt = 0; mt < cnt; mt += 64) {
        float acc[4][4] = {};
        int m = mt + arow;
        const float* Arow = nullptr;
        if (m < cnt) {
            if (phase == 1) Arow = Abase + (size_t)rows_tv[off + m] * DMODEL;
            else            Arow = Abase + (size_t)(off + m) * HFF;
        }
        for (int kp = 0; kp < K; kp += 16) {
            float4 av = make_float4(0.f, 0.f, 0.f, 0.f);
            if (Arow) av = *(const float4*)(Arow + kp + ac4);
            As[ac4 + 0][arow] = av.x; As[ac4 + 1][arow] = av.y;
            As[ac4 + 2][arow] = av.z; As[ac4 + 3][arow] = av.w;
            float4 wvv = *(const float4*)(W + (size_t)(kp + wrow) * N + n0 + wc4);
            *(float4*)&Ws[wrow][wc4] = wvv;
            __syncthreads();
#pragma unroll
            for (int k = 0; k < 16; ++k) {
                float4 a = *(const float4*)&As[k][ty * 4];
                float4 b = *(const float4*)&Ws[k][tx * 4];
                acc[0][0] += a.x * b.x; acc[0][1] += a.x * b.y; acc[0][2] += a.x * b.z; acc[0][3] += a.x * b.w;
                acc[1][0] += a.y * b.x; acc[1][1] += a.y * b.y; acc[1][2] += a.y * b.z; acc[1][3] += a.y * b.w;
                acc[2][0] += a.z * b.x; acc[2][1] += a.z * b.y; acc[2][2] += a.z * b.z; acc[2][3] += a.z * b.w;
                acc[3][0] += a.w * b.x; acc[3][1] += a.w * b.y; acc[3][2] += a.w * b.z; acc[3][3] += a.w * b.w;
            }
            __syncthreads();
        }
        for (int i = 0; i < 4; ++i) {
            int m2 = mt + ty * 4 + i;
            if (m2 < cnt) {
                float* Crow;
                if (phase == 1) Crow = Cbase + (size_t)(off + m2) * N;
                else            Crow = Cbase + (size_t)rows_s[off + m2] * N;
                int col = n0 + tx * 4;
                float4 b4 = *(const float4*)(bias + col);
                float4 c;
                c.x = acc[i][0] + b4.x; c.y = acc[i][1] + b4.y;
                c.z = acc[i][2] + b4.z; c.w = acc[i][3] + b4.w;
                if (phase == 1) {
                    c.x = gelu_exact(c.x); c.y = gelu_exact(c.y);
                    c.z = gelu_exact(c.z); c.w = gelu_exact(c.w);
                }
                *(float4*)(Crow + col) = c;
            }
        }
    }
}

// ---------------- dense GEMM: C[M,N] = act(A[M,K] @ W[K,N] + bias) ----------------
__global__ __launch_bounds__(256) void gemm_dense(
    const float* __restrict__ A, const float* __restrict__ W,
    const float* __restrict__ bias, float* __restrict__ C,
    int M, int N, int K, int act)
{
    int n0 = blockIdx.x * 64;
    int m0 = blockIdx.y * 64;
    __shared__ float As[16][64];
    __shared__ float Ws[16][64];
    int tid = threadIdx.x;
    int tx = tid & 15, ty = tid >> 4;
    int arow = tid >> 2, ac4 = (tid & 3) * 4;
    int wrow = tid >> 4, wc4 = (tid & 15) * 4;

    float acc[4][4] = {};
    int m = m0 + arow;
    const float* Arow = (m < M) ? (A + (size_t)m * K) : nullptr;

    for (int kp = 0; kp < K; kp += 16) {
        float4 av = make_float4(0.f, 0.f, 0.f, 0.f);
        if (Arow) av = *(const float4*)(Arow + kp + ac4);
        As[ac4 + 0][arow] = av.x; As[ac4 + 1][arow] = av.y;
        As[ac4 + 2][arow] = av.z; As[ac4 + 3][arow] = av.w;
        float4 wvv = *(const float4*)(W + (size_t)(kp + wrow) * N + n0 + wc4);
        *(float4*)&Ws[wrow][wc4] = wvv;
        __syncthreads();
#pragma unroll
        for (int k = 0; k < 16; ++k) {
            float4 a = *(const float4*)&As[k][ty * 4];
            float4 b = *(const float4*)&Ws[k][tx * 4];
            acc[0][0] += a.x * b.x; acc[0][1] += a.x * b.y; acc[0][2] += a.x * b.z; acc[0][3] += a.x * b.w;
            acc[1][0] += a.y * b.x; acc[1][1] += a.y * b.y; acc[1][2] += a.y * b.z; acc[1][3] += a.y * b.w;
            acc[2][0] += a.z * b.x; acc[2][1] += a.z * b.y; acc[2][2] += a.z * b.z; acc[2][3] += a.z * b.w;
            acc[3][0] += a.w * b.x; acc[3][1] += a.w * b.y; acc[3][2] += a.w * b.z; acc[3][3] += a.w * b.w;
        }
        __syncthreads();
    }
    for (int i = 0; i < 4; ++i) {
        int row = m0 + ty * 4 + i;
        if (row < M) {
            int col = n0 + tx * 4;
            float4 b4 = *(const float4*)(bias + col);
            float4 c;
            c.x = acc[i][0] + b4.x; c.y = acc[i][1] + b4.y;
            c.z = acc[i][2] + b4.z; c.w = acc[i][3] + b4.w;
            if (act == 1) {
                c.x = fmaxf(c.x, 0.f); c.y = fmaxf(c.y, 0.f);
                c.z = fmaxf(c.z, 0.f); c.w = fmaxf(c.w, 0.f);
            }
            *(float4*)(C + (size_t)row * N + col) = c;
        }
    }
}

// ---------------- fuse: weighted MoE gather + fractional PE ----------------
__global__ __launch_bounds__(256) void fuse_kernel(
    const float* __restrict__ y_all, const float* __restrict__ w4,
    const float* __restrict__ frac, float* __restrict__ x)
{
    int t = blockIdx.x;
    int tid = threadIdx.x;
    __shared__ float wsh[12];
    __shared__ int idxsh[2];
    if (tid < 12) {
        int vi = tid >> 2, kk = tid & 3;
        wsh[tid] = w4[((size_t)vi * NTOK + t) * TOPK + kk];
    }
    if (tid == 0) {
        double r = (double)frac[t];
        double rl = fmax(r, 1.0 / RESN);
        int il = (int)rint(rl * RESN) - 1;
        idxsh[0] = min(max(il, 0), RESN - 1);
        double lg = log2(r);
        double rg = 0.0025 * lg * lg;
        rg = fmin(rg, 1.0);
        rg = fmax(rg, 1.0 / RESN);
        int ig = (int)rint(rg * RESN) - 1;
        idxsh[1] = min(max(ig, 0), RESN - 1);
    }
    __syncthreads();
    for (int d = tid; d < DMODEL; d += 256) {
        float acc = 0.0f;
        for (int c = 0; c < 12; ++c) {
            int vi = c >> 2, kk = c & 3;
            size_t s = ((size_t)vi * NTOK + t) * TOPK + kk;
            acc += wsh[c] * y_all[s * DMODEL + d];
        }
        int cc  = (d < 256) ? d : d - 256;
        int idx = (d < 256) ? idxsh[0] : idxsh[1];
        double arg = (double)idx / pow(50.0, 2.0 * (double)cc / 256.0);
        double pe = (cc & 1) ? cos(arg) : sin(arg);
        x[(size_t)t * DMODEL + d] = acc + (float)pe;
    }
}

// ---------------- attention (one block per (b,head)) ----------------
__global__ __launch_bounds__(64) void attn_kernel(
    const float* __restrict__ qkv, float* __restrict__ o)
{
    int bh = blockIdx.x;
    int b = bh >> 3, hh = bh & 7;
    int t0 = b * 9;
    __shared__ float q[9][64], k[9][64], v[9][64], sc[81], p[9][9];
    int t = threadIdx.x;
    for (int i = 0; i < 9; ++i) {
        const float* row = qkv + (size_t)(t0 + i) * 1536 + hh * 64 + t;
        q[i][t] = row[0]; k[i][t] = row[512]; v[i][t] = row[1024];
    }
    __syncthreads();
    for (int ij = t; ij < 81; ij += 64) {
        int i = ij / 9, j = ij % 9;
        float s = 0.0f;
        for (int d = 0; d < 64; ++d) s += q[i][d] * k[j][d];
        sc[ij] = s * 0.125f;
    }
    __syncthreads();
    if (t < 9) {
        float m = -1e30f;
        for (int j = 0; j < 9; ++j) m = fmaxf(m, sc[t * 9 + j]);
        float sum = 0.0f, e[9];
        for (int j = 0; j < 9; ++j) { e[j] = expf(sc[t * 9 + j] - m); sum += e[j]; }
        for (int j = 0; j < 9; ++j) p[t][j] = e[j] / sum;
    }
    __syncthreads();
    for (int i = 0; i < 9; ++i) {
        float acc = 0.0f;
        for (int j = 0; j < 9; ++j) acc += p[i][j] * v[j][t];
        o[(size_t)(t0 + i) * DMODEL + hh * 64 + t] = acc;
    }
}

// ---------------- residual + layernorm ----------------
__global__ __launch_bounds__(256) void ln_kernel(
    float* __restrict__ x, const float* __restrict__ r,
    const float* __restrict__ g, const float* __restrict__ b)
{
    int t = blockIdx.x;
    int tid = threadIdx.x;
    __shared__ float red[256];
    __shared__ float stat;
    size_t base = (size_t)t * DMODEL;
    float v0 = x[base + tid] + r[base + tid];
    float v1 = x[base + 256 + tid] + r[base + 256 + tid];
    red[tid] = v0 + v1;
    __syncthreads();
    for (int s = 128; s > 0; s >>= 1) { if (tid < s) red[tid] += red[tid + s]; __syncthreads(); }
    if (tid == 0) stat = red[0] * (1.0f / DMODEL);
    __syncthreads();
    float m = stat;
    float d0 = v0 - m, d1 = v1 - m;
    red[tid] = d0 * d0 + d1 * d1;
    __syncthreads();
    for (int s = 128; s > 0; s >>= 1) { if (tid < s) red[tid] += red[tid + s]; __syncthreads(); }
    if (tid == 0) stat = rsqrtf(red[0] * (1.0f / DMODEL) + 1e-5f);
    __syncthreads();
    float is = stat;
    x[base + tid]       = d0 * is * g[tid] + b[tid];
    x[base + 256 + tid] = d1 * is * g[256 + tid] + b[256 + tid];
}

// ---------------- final scale ----------------
__global__ __launch_bounds__(256) void finalize_kernel(
    const float* __restrict__ x, const float* __restrict__ frac, float* __restrict__ out)
{
    int i = blockIdx.x * 256 + threadIdx.x;
    out[i] = x[i] * frac[i >> 9];
}

extern "C" void kernel_launch(void* const* d_in, const int* in_sizes, int n_in,
                              void* d_out, int out_size, void* d_ws, size_t ws_size,
                              hipStream_t stream) {
    const int*   Z      = (const int*)d_in[0];
    const float* frac   = (const float*)d_in[1];
    const float* emb0   = (const float*)d_in[2];
    const float* p0w    = (const float*)d_in[3];
    const float* p0b    = (const float*)d_in[4];
    const float* emb1   = (const float*)d_in[5];
    const float* p1w    = (const float*)d_in[6];
    const float* p1b    = (const float*)d_in[7];
    const float* emb2   = (const float*)d_in[8];
    const float* p2w    = (const float*)d_in[9];
    const float* p2b    = (const float*)d_in[10];
    const float* keys   = (const float*)d_in[11];
    const float* rw     = (const float*)d_in[12];
    const float* rb     = (const float*)d_in[13];
    const float* ew1    = (const float*)d_in[14];
    const float* eb1    = (const float*)d_in[15];
    const float* ew2    = (const float*)d_in[16];
    const float* eb2    = (const float*)d_in[17];
    const float* qkv_w  = (const float*)d_in[18];
    const float* qkv_b  = (const float*)d_in[19];
    const float* aow    = (const float*)d_in[20];
    const float* aob    = (const float*)d_in[21];
    const float* ln1g   = (const float*)d_in[22];
    const float* ln1b   = (const float*)d_in[23];
    const float* ln2g   = (const float*)d_in[24];
    const float* ln2b   = (const float*)d_in[25];
    const float* fw1    = (const float*)d_in[26];
    const float* fb1    = (const float*)d_in[27];
    const float* fw2    = (const float*)d_in[28];
    const float* fb2    = (const float*)d_in[29];
    float* out = (float*)d_out;

    // workspace layout (floats)
    float* wsf   = (float*)d_ws;
    float* v     = wsf;                       // 864*512   = 442368
    float* h     = v + 442368;                // 3456*2048 = 7077888
    float* yall  = h + 7077888;               // 3456*512  = 1769472
    float* xbuf  = yall + 1769472;            // 288*512   = 147456
    float* qkvb  = xbuf + 147456;             // 288*1536  = 442368
    float* obuf  = qkvb + 442368;             // 288*512
    float* tmp   = obuf + 147456;             // 288*512
    float* f1    = tmp + 147456;              // 288*2048  = 589824
    float* w4    = f1 + 589824;               // 3456
    int* idx4    = (int*)(w4 + 3456);         // 3456
    int* offs    = idx4 + 3456;               // 17 (pad 32)
    int* rows_tv = offs + 32;                 // 3456
    int* rows_s  = rows_tv + 3456;            // 3456

    build_tokens<<<dim3(NTV), dim3(256), 0, stream>>>(
        Z, emb0, p0w, p0b, emb1, p1w, p1b, emb2, p2w, p2b,
        keys, rw, rb, v, w4, idx4);

    route_kernel<<<dim3(1), dim3(256), 0, stream>>>(idx4, offs, rows_tv, rows_s);

    gemm_moe<<<dim3(HFF / 64, NEXP), dim3(256), 0, stream>>>(
        v, rows_tv, rows_s, offs, ew1, eb1, h, HFF, DMODEL, 1);
    gemm_moe<<<dim3(DMODEL / 64, NEXP), dim3(256), 0, stream>>>(
        h, rows_tv, rows_s, offs, ew2, eb2, yall, DMODEL, HFF, 2);

    fuse_kernel<<<dim3(NTOK), dim3(256), 0, stream>>>(yall, w4, frac, xbuf);

    for (int i = 0; i < 3; ++i) {
        gemm_dense<<<dim3(1536 / 64, 5), dim3(256), 0, stream>>>(
            xbuf, qkv_w + (size_t)i * 512 * 1536, qkv_b + i * 1536, qkvb, NTOK, 1536, 512, 0);
        attn_kernel<<<dim3(256), dim3(64), 0, stream>>>(qkvb, obuf);
        gemm_dense<<<dim3(512 / 64, 5), dim3(256), 0, stream>>>(
            obuf, aow + (size_t)i * 512 * 512, aob + i * 512, tmp, NTOK, 512, 512, 0);
        ln_kernel<<<dim3(NTOK), dim3(256), 0, stream>>>(xbuf, tmp, ln1g + i * 512, ln1b + i * 512);
        gemm_dense<<<dim3(2048 / 64, 5), dim3(256), 0, stream>>>(
            xbuf, fw1 + (size_t)i * 512 * 2048, fb1 + i * 2048, f1, NTOK, 2048, 512, 1);
        gemm_dense<<<dim3(512 / 64, 5), dim3(256), 0, stream>>>(
            f1, fw2 + (size_t)i * 2048 * 512, fb2 + i * 512, tmp, NTOK, 512, 2048, 0);
        ln_kernel<<<dim3(NTOK), dim3(256), 0, stream>>>(xbuf, tmp, ln2g + i * 512, ln2b + i * 512);
    }

    finalize_kernel<<<dim3(NTOK * DMODEL / 256), dim3(256), 0, stream>>>(xbuf, frac, out);
}

// Round 2
// 674.187 us; speedup vs baseline: 2.8925x; 2.8925x over previous
//
#include <hip/hip_runtime.h>
#include <hip/hip_bf16.h>
#include <math.h>

#define NTOK   288      // B*L
#define NV     3
#define NTV    864      // NV*NTOK
#define NSEL   3456     // NTV*4
#define DMODEL 512
#define NEXP   16
#define TOPK   4
#define HFF    2048
#define RESN   5000

typedef short v8s __attribute__((ext_vector_type(8)));
typedef float v4f __attribute__((ext_vector_type(4)));

__device__ __forceinline__ float gelu_exact(float x) {
    return 0.5f * x * (1.0f + erff(x * 0.70710678118654752f));
}
__device__ __forceinline__ unsigned f2bf1(float f) {
    unsigned u = __builtin_bit_cast(unsigned, f);
    return (u + 0x7fffu + ((u >> 16) & 1u)) >> 16;
}
__device__ __forceinline__ unsigned pack2(float a, float b) {
    return f2bf1(a) | (f2bf1(b) << 16);
}

// ---------------- K0: views + router + top-k ----------------
__global__ __launch_bounds__(256) void build_tokens(
    const int* __restrict__ Z,
    const float* __restrict__ emb0, const float* __restrict__ p0w, const float* __restrict__ p0b,
    const float* __restrict__ emb1, const float* __restrict__ p1w, const float* __restrict__ p1b,
    const float* __restrict__ emb2, const float* __restrict__ p2w, const float* __restrict__ p2b,
    const float* __restrict__ keys, const float* __restrict__ router_w, const float* __restrict__ router_b,
    float* __restrict__ v_out, float* __restrict__ w4, int* __restrict__ idx4)
{
    int tv = blockIdx.x;
    int vi = tv / NTOK, t = tv % NTOK;
    int tid = threadIdx.x;

    const float* emb; const float* pw; const float* pb; int F;
    if (vi == 0)      { emb = emb0; pw = p0w; pb = p0b; F = 200; }
    else if (vi == 1) { emb = emb1; pw = p1w; pb = p1b; F = 132; }
    else              { emb = emb2; pw = p2w; pb = p2b; F = 112; }
    const float* rw = router_w + (size_t)vi * DMODEL * NEXP;
    const float* rb = router_b + vi * NEXP;

    __shared__ float er[200];
    __shared__ float vs[DMODEL];
    __shared__ float red[256];
    __shared__ float logits[NEXP];
    __shared__ float vsq_s;

    int z = Z[t];
    for (int f = tid; f < F; f += 256) er[f] = emb[(size_t)z * F + f];
    __syncthreads();

    float a0 = pb[tid], a1 = pb[tid + 256];
    for (int f = 0; f < F; ++f) {
        float e = er[f];
        a0 += e * pw[f * DMODEL + tid];
        a1 += e * pw[f * DMODEL + tid + 256];
    }
    vs[tid] = a0; vs[tid + 256] = a1;
    v_out[(size_t)tv * DMODEL + tid] = a0;
    v_out[(size_t)tv * DMODEL + tid + 256] = a1;

    red[tid] = a0 * a0 + a1 * a1;
    __syncthreads();
    for (int s = 128; s > 0; s >>= 1) { if (tid < s) red[tid] += red[tid + s]; __syncthreads(); }
    if (tid == 0) vsq_s = red[0];
    __syncthreads();
    float vsq = vsq_s;

    int lane = tid & 63, wv = tid >> 6;
    for (int ei = 0; ei < 4; ++ei) {
        int e = wv * 4 + ei;
        float p = 0.0f;
        for (int d = lane; d < DMODEL; d += 64) {
            float vvv = vs[d];
            float kk = keys[e * DMODEL + d];
            p += vvv * rw[d * NEXP + e] - kk * (kk - 2.0f * vvv);
        }
        for (int off = 32; off > 0; off >>= 1) p += __shfl_down(p, off, 64);
        if (lane == 0) logits[e] = -vsq + p + rb[e];
    }
    __syncthreads();

    if (tid == 0) {
        float lv[NEXP];
        for (int e = 0; e < NEXP; ++e) lv[e] = logits[e];
        bool used[NEXP] = {false};
        int   tk[TOPK]; float tval[TOPK];
        for (int k = 0; k < TOPK; ++k) {
            int best = -1; float bv = -1e30f;
            for (int e = 0; e < NEXP; ++e)
                if (!used[e] && lv[e] > bv) { bv = lv[e]; best = e; }
            used[best] = true; tk[k] = best; tval[k] = bv;
        }
        float m = tval[0], sum = 0.0f, ww[TOPK];
        for (int k = 0; k < TOPK; ++k) { ww[k] = expf(tval[k] - m); sum += ww[k]; }
        for (int k = 0; k < TOPK; ++k) {
            w4[tv * TOPK + k] = ww[k] / sum;
            idx4[tv * TOPK + k] = tk[k];
        }
    }
}

// ---------------- K1: compact rows per expert ----------------
__global__ __launch_bounds__(256) void route_kernel(
    const int* __restrict__ idx4, int* __restrict__ offs,
    int* __restrict__ rows_tv, int* __restrict__ rows_s)
{
    __shared__ int cnt[NEXP], cur[NEXP], offsh[NEXP + 1];
    int tid = threadIdx.x;
    if (tid < NEXP) cnt[tid] = 0;
    __syncthreads();
    for (int s = tid; s < NSEL; s += 256) atomicAdd(&cnt[idx4[s]], 1);
    __syncthreads();
    if (tid == 0) {
        int o = 0;
        for (int e = 0; e < NEXP; ++e) { offsh[e] = o; o += cnt[e]; }
        offsh[NEXP] = o;
    }
    __syncthreads();
    if (tid < NEXP) cur[tid] = offsh[tid];
    if (tid <= NEXP) offs[tid] = offsh[tid];
    __syncthreads();
    for (int s = tid; s < NSEL; s += 256) {
        int e = idx4[s];
        int pos = atomicAdd(&cur[e], 1);
        rows_tv[pos] = s >> 2;
        rows_s[pos]  = s;
    }
}

// ---------------- transpose + fp32->bf16: in [b][K][N] -> out [b][N][K] ----------------
__global__ __launch_bounds__(256) void transpose_to_bf16(
    const float* __restrict__ in, unsigned short* __restrict__ out, int K, int N)
{
    size_t boff = (size_t)blockIdx.z * (size_t)K * N;
    const float* src_b = in + boff;
    unsigned short* out_b = out + boff;
    int n0 = blockIdx.x * 64, k0 = blockIdx.y * 64;
    __shared__ unsigned short T[64 * 72];
    int t = threadIdx.x, r = t >> 2, c = t & 3;

    const float* src = src_b + (size_t)(k0 + r) * N + n0 + c * 16;
    float4 f0 = *(const float4*)(src + 0);
    float4 f1 = *(const float4*)(src + 4);
    float4 f2 = *(const float4*)(src + 8);
    float4 f3 = *(const float4*)(src + 12);
    uint4 u0, u1;
    u0.x = pack2(f0.x, f0.y); u0.y = pack2(f0.z, f0.w);
    u0.z = pack2(f1.x, f1.y); u0.w = pack2(f1.z, f1.w);
    u1.x = pack2(f2.x, f2.y); u1.y = pack2(f2.z, f2.w);
    u1.z = pack2(f3.x, f3.y); u1.w = pack2(f3.z, f3.w);
    *(uint4*)&T[r * 72 + c * 16]     = u0;
    *(uint4*)&T[r * 72 + c * 16 + 8] = u1;
    __syncthreads();

    uint4 o0, o1;
    unsigned* op = (unsigned*)&o0;
#pragma unroll
    for (int j = 0; j < 16; j += 2) {
        unsigned lo = T[(c * 16 + j)     * 72 + r];
        unsigned hi = T[(c * 16 + j + 1) * 72 + r];
        if (j < 8) op[j >> 1] = lo | (hi << 16);
        else ((unsigned*)&o1)[(j - 8) >> 1] = lo | (hi << 16);
    }
    unsigned short* dst = out_b + (size_t)(n0 + r) * K + k0 + c * 16;
    *(uint4*)(dst)     = o0;
    *(uint4*)(dst + 8) = o1;
}

// ---------------- MoE MFMA GEMM (64x64 tile, BK=64) ----------------
// phase 1: A = v fp32 (rows via rows_tv), Wt = ew1^T bf16, out = h bf16 (gelu), N=2048,K=512
// phase 2: A = h bf16 (rows off+m),       Wt = ew2^T bf16, out = yall fp32 via rows_s, N=512,K=2048
__global__ __launch_bounds__(256) void gemm_moe_mfma(
    const float* __restrict__ Afp, const unsigned short* __restrict__ Abf,
    const int* __restrict__ rows_tv, const int* __restrict__ rows_s,
    const int* __restrict__ offs,
    const unsigned short* __restrict__ Wt, const float* __restrict__ Bbase,
    unsigned short* __restrict__ Cbf, float* __restrict__ Cf,
    int N, int K, int phase)
{
    int e = blockIdx.y;
    int off = offs[e], cnt = offs[e + 1] - off;
    int mt = blockIdx.z * 64;
    if (mt >= cnt) return;
    int n0 = blockIdx.x * 64;
    const unsigned short* W = Wt + (size_t)e * N * K;
    const float* bias = Bbase + (size_t)e * N;

    __shared__ unsigned short As[64 * 64];
    __shared__ unsigned short Bs[64 * 64];
    int tid = threadIdx.x, r = tid >> 2, c = tid & 3;
    int wave = tid >> 6, lane = tid & 63, lq = lane >> 4, lm = lane & 15;

    int m = mt + r;
    bool mv = m < cnt;
    const float* arow_f = nullptr; const unsigned short* arow_b = nullptr;
    if (phase == 1) { if (mv) arow_f = Afp + (size_t)rows_tv[off + m] * DMODEL; }
    else            { if (mv) arow_b = Abf + (size_t)(off + m) * HFF; }
    const unsigned short* wrow = W + (size_t)(n0 + r) * K;

    v4f acc[4];
#pragma unroll
    for (int nt = 0; nt < 4; ++nt) acc[nt] = (v4f){0.f, 0.f, 0.f, 0.f};

    for (int kp = 0; kp < K; kp += 64) {
        uint4 a0 = {0,0,0,0}, a1 = {0,0,0,0};
        if (phase == 1) {
            if (mv) {
                const float* s = arow_f + kp + c * 16;
                float4 f0 = *(const float4*)(s + 0);
                float4 f1 = *(const float4*)(s + 4);
                float4 f2 = *(const float4*)(s + 8);
                float4 f3 = *(const float4*)(s + 12);
                a0.x = pack2(f0.x, f0.y); a0.y = pack2(f0.z, f0.w);
                a0.z = pack2(f1.x, f1.y); a0.w = pack2(f1.z, f1.w);
                a1.x = pack2(f2.x, f2.y); a1.y = pack2(f2.z, f2.w);
                a1.z = pack2(f3.x, f3.y); a1.w = pack2(f3.z, f3.w);
            }
        } else {
            if (mv) {
                const unsigned short* s = arow_b + kp + c * 16;
                a0 = *(const uint4*)(s);
                a1 = *(const uint4*)(s + 8);
            }
        }
        *(uint4*)&As[r * 64 + c * 16]     = a0;
        *(uint4*)&As[r * 64 + c * 16 + 8] = a1;

        const unsigned short* ws = wrow + kp + c * 16;
        uint4 b0 = *(const uint4*)(ws);
        uint4 b1 = *(const uint4*)(ws + 8);
        *(uint4*)&Bs[r * 64 + c * 16]     = b0;
        *(uint4*)&Bs[r * 64 + c * 16 + 8] = b1;
        __syncthreads();

        const unsigned short* aBase = &As[(wave * 16 + lm) * 64];
#pragma unroll
        for (int s = 0; s < 64; s += 32) {
            v8s a = *(const v8s*)(aBase + s + lq * 8);
#pragma unroll
            for (int nt = 0; nt < 4; ++nt) {
                v8s b = *(const v8s*)(&Bs[(nt * 16 + lm) * 64 + s + lq * 8]);
                acc[nt] = __builtin_amdgcn_mfma_f32_16x16x32_bf16(a, b, acc[nt], 0, 0, 0);
            }
        }
        __syncthreads();
    }

#pragma unroll
    for (int nt = 0; nt < 4; ++nt) {
        int col = n0 + nt * 16 + lm;
        float bv = bias[col];
#pragma unroll
        for (int i = 0; i < 4; ++i) {
            int m2 = mt + wave * 16 + lq * 4 + i;
            if (m2 < cnt) {
                float val = acc[nt][i] + bv;
                if (phase == 1) {
                    val = gelu_exact(val);
                    Cbf[(size_t)(off + m2) * N + col] = (unsigned short)f2bf1(val);
                } else {
                    Cf[(size_t)rows_s[off + m2] * N + col] = val;
                }
            }
        }
    }
}

// ---------------- dense MFMA GEMM: C[M,N] = act(A[M,K] @ Wt^T + bias) ----------------
__global__ __launch_bounds__(256) void gemm_dense_mfma(
    const float* __restrict__ A, const unsigned short* __restrict__ Wt,
    const float* __restrict__ bias, float* __restrict__ C,
    int M, int N, int K, int act)
{
    int n0 = blockIdx.x * 64;
    int m0 = blockIdx.y * 64;
    __shared__ unsigned short As[64 * 64];
    __shared__ unsigned short Bs[64 * 64];
    int tid = threadIdx.x, r = tid >> 2, c = tid & 3;
    int wave = tid >> 6, lane = tid & 63, lq = lane >> 4, lm = lane & 15;

    int m = m0 + r;
    bool mv = m < M;
    const float* arow = mv ? (A + (size_t)m * K) : nullptr;
    const unsigned short* wrow = Wt + (size_t)(n0 + r) * K;

    v4f acc[4];
#pragma unroll
    for (int nt = 0; nt < 4; ++nt) acc[nt] = (v4f){0.f, 0.f, 0.f, 0.f};

    for (int kp = 0; kp < K; kp += 64) {
        uint4 a0 = {0,0,0,0}, a1 = {0,0,0,0};
        if (mv) {
            const float* s = arow + kp + c * 16;
            float4 f0 = *(const float4*)(s + 0);
            float4 f1 = *(const float4*)(s + 4);
            float4 f2 = *(const float4*)(s + 8);
            float4 f3 = *(const float4*)(s + 12);
            a0.x = pack2(f0.x, f0.y); a0.y = pack2(f0.z, f0.w);
            a0.z = pack2(f1.x, f1.y); a0.w = pack2(f1.z, f1.w);
            a1.x = pack2(f2.x, f2.y); a1.y = pack2(f2.z, f2.w);
            a1.z = pack2(f3.x, f3.y); a1.w = pack2(f3.z, f3.w);
        }
        *(uint4*)&As[r * 64 + c * 16]     = a0;
        *(uint4*)&As[r * 64 + c * 16 + 8] = a1;

        const unsigned short* ws = wrow + kp + c * 16;
        uint4 b0 = *(const uint4*)(ws);
        uint4 b1 = *(const uint4*)(ws + 8);
        *(uint4*)&Bs[r * 64 + c * 16]     = b0;
        *(uint4*)&Bs[r * 64 + c * 16 + 8] = b1;
        __syncthreads();

        const unsigned short* aBase = &As[(wave * 16 + lm) * 64];
#pragma unroll
        for (int s = 0; s < 64; s += 32) {
            v8s a = *(const v8s*)(aBase + s + lq * 8);
#pragma unroll
            for (int nt = 0; nt < 4; ++nt) {
                v8s b = *(const v8s*)(&Bs[(nt * 16 + lm) * 64 + s + lq * 8]);
                acc[nt] = __builtin_amdgcn_mfma_f32_16x16x32_bf16(a, b, acc[nt], 0, 0, 0);
            }
        }
        __syncthreads();
    }

#pragma unroll
    for (int nt = 0; nt < 4; ++nt) {
        int col = n0 + nt * 16 + lm;
        float bv = bias[col];
#pragma unroll
        for (int i = 0; i < 4; ++i) {
            int row = m0 + wave * 16 + lq * 4 + i;
            if (row < M) {
                float val = acc[nt][i] + bv;
                if (act == 1) val = fmaxf(val, 0.f);
                C[(size_t)row * N + col] = val;
            }
        }
    }
}

// ---------------- fuse: weighted MoE gather + fractional PE ----------------
__global__ __launch_bounds__(256) void fuse_kernel(
    const float* __restrict__ y_all, const float* __restrict__ w4,
    const float* __restrict__ frac, float* __restrict__ x)
{
    int t = blockIdx.x;
    int tid = threadIdx.x;
    __shared__ float wsh[12];
    __shared__ int idxsh[2];
    if (tid < 12) {
        int vi = tid >> 2, kk = tid & 3;
        wsh[tid] = w4[((size_t)vi * NTOK + t) * TOPK + kk];
    }
    if (tid == 0) {
        double r = (double)frac[t];
        double rl = fmax(r, 1.0 / RESN);
        int il = (int)rint(rl * RESN) - 1;
        idxsh[0] = min(max(il, 0), RESN - 1);
        double lg = log2(r);
        double rg = 0.0025 * lg * lg;
        rg = fmin(rg, 1.0);
        rg = fmax(rg, 1.0 / RESN);
        int ig = (int)rint(rg * RESN) - 1;
        idxsh[1] = min(max(ig, 0), RESN - 1);
    }
    __syncthreads();
    for (int d = tid; d < DMODEL; d += 256) {
        float acc = 0.0f;
        for (int c = 0; c < 12; ++c) {
            int vi = c >> 2, kk = c & 3;
            size_t s = ((size_t)vi * NTOK + t) * TOPK + kk;
            acc += wsh[c] * y_all[s * DMODEL + d];
        }
        int cc  = (d < 256) ? d : d - 256;
        int idx = (d < 256) ? idxsh[0] : idxsh[1];
        double arg = (double)idx / pow(50.0, 2.0 * (double)cc / 256.0);
        double pe = (cc & 1) ? cos(arg) : sin(arg);
        x[(size_t)t * DMODEL + d] = acc + (float)pe;
    }
}

// ---------------- attention ----------------
__global__ __launch_bounds__(64) void attn_kernel(
    const float* __restrict__ qkv, float* __restrict__ o)
{
    int bh = blockIdx.x;
    int b = bh >> 3, hh = bh & 7;
    int t0 = b * 9;
    __shared__ float q[9][64], k[9][64], v[9][64], sc[81], p[9][9];
    int t = threadIdx.x;
    for (int i = 0; i < 9; ++i) {
        const float* row = qkv + (size_t)(t0 + i) * 1536 + hh * 64 + t;
        q[i][t] = row[0]; k[i][t] = row[512]; v[i][t] = row[1024];
    }
    __syncthreads();
    for (int ij = t; ij < 81; ij += 64) {
        int i = ij / 9, j = ij % 9;
        float s = 0.0f;
        for (int d = 0; d < 64; ++d) s += q[i][d] * k[j][d];
        sc[ij] = s * 0.125f;
    }
    __syncthreads();
    if (t < 9) {
        float m = -1e30f;
        for (int j = 0; j < 9; ++j) m = fmaxf(m, sc[t * 9 + j]);
        float sum = 0.0f, e[9];
        for (int j = 0; j < 9; ++j) { e[j] = expf(sc[t * 9 + j] - m); sum += e[j]; }
        for (int j = 0; j < 9; ++j) p[t][j] = e[j] / sum;
    }
    __syncthreads();
    for (int i = 0; i < 9; ++i) {
        float acc = 0.0f;
        for (int j = 0; j < 9; ++j) acc += p[i][j] * v[j][t];
        o[(size_t)(t0 + i) * DMODEL + hh * 64 + t] = acc;
    }
}

// ---------------- residual + layernorm ----------------
__global__ __launch_bounds__(256) void ln_kernel(
    float* __restrict__ x, const float* __restrict__ r,
    const float* __restrict__ g, const float* __restrict__ b)
{
    int t = blockIdx.x;
    int tid = threadIdx.x;
    __shared__ float red[256];
    __shared__ float stat;
    size_t base = (size_t)t * DMODEL;
    float v0 = x[base + tid] + r[base + tid];
    float v1 = x[base + 256 + tid] + r[base + 256 + tid];
    red[tid] = v0 + v1;
    __syncthreads();
    for (int s = 128; s > 0; s >>= 1) { if (tid < s) red[tid] += red[tid + s]; __syncthreads(); }
    if (tid == 0) stat = red[0] * (1.0f / DMODEL);
    __syncthreads();
    float m = stat;
    float d0 = v0 - m, d1 = v1 - m;
    red[tid] = d0 * d0 + d1 * d1;
    __syncthreads();
    for (int s = 128; s > 0; s >>= 1) { if (tid < s) red[tid] += red[tid + s]; __syncthreads(); }
    if (tid == 0) stat = rsqrtf(red[0] * (1.0f / DMODEL) + 1e-5f);
    __syncthreads();
    float is = stat;
    x[base + tid]       = d0 * is * g[tid] + b[tid];
    x[base + 256 + tid] = d1 * is * g[256 + tid] + b[256 + tid];
}

// ---------------- final scale ----------------
__global__ __launch_bounds__(256) void finalize_kernel(
    const float* __restrict__ x, const float* __restrict__ frac, float* __restrict__ out)
{
    int i = blockIdx.x * 256 + threadIdx.x;
    out[i] = x[i] * frac[i >> 9];
}

extern "C" void kernel_launch(void* const* d_in, const int* in_sizes, int n_in,
                              void* d_out, int out_size, void* d_ws, size_t ws_size,
                              hipStream_t stream) {
    const int*   Z      = (const int*)d_in[0];
    const float* frac   = (const float*)d_in[1];
    const float* emb0   = (const float*)d_in[2];
    const float* p0w    = (const float*)d_in[3];
    const float* p0b    = (const float*)d_in[4];
    const float* emb1   = (const float*)d_in[5];
    const float* p1w    = (const float*)d_in[6];
    const float* p1b    = (const float*)d_in[7];
    const float* emb2   = (const float*)d_in[8];
    const float* p2w    = (const float*)d_in[9];
    const float* p2b    = (const float*)d_in[10];
    const float* keys   = (const float*)d_in[11];
    const float* rw     = (const float*)d_in[12];
    const float* rb     = (const float*)d_in[13];
    const float* ew1    = (const float*)d_in[14];
    const float* eb1    = (const float*)d_in[15];
    const float* ew2    = (const float*)d_in[16];
    const float* eb2    = (const float*)d_in[17];
    const float* qkv_w  = (const float*)d_in[18];
    const float* qkv_b  = (const float*)d_in[19];
    const float* aow    = (const float*)d_in[20];
    const float* aob    = (const float*)d_in[21];
    const float* ln1g   = (const float*)d_in[22];
    const float* ln1b   = (const float*)d_in[23];
    const float* ln2g   = (const float*)d_in[24];
    const float* ln2b   = (const float*)d_in[25];
    const float* fw1    = (const float*)d_in[26];
    const float* fb1    = (const float*)d_in[27];
    const float* fw2    = (const float*)d_in[28];
    const float* fb2    = (const float*)d_in[29];
    float* out = (float*)d_out;

    // workspace layout (bytes, all 256-aligned)
    char* p = (char*)d_ws;
    float* v    = (float*)p;            p += 864 * 512 * 4;          // 1.77 MB
    unsigned short* h = (unsigned short*)p; p += 3456 * 2048 * 2;    // 14.2 MB
    float* yall = (float*)p;            p += 3456 * 512 * 4;         // 7.1 MB
    float* xbuf = (float*)p;            p += 288 * 512 * 4;
    float* qkvb = (float*)p;            p += 288 * 1536 * 4;
    float* obuf = (float*)p;            p += 288 * 512 * 4;
    float* tmp  = (float*)p;            p += 288 * 512 * 4;
    float* f1   = (float*)p;            p += 288 * 2048 * 4;
    float* w4   = (float*)p;            p += 3456 * 4;
    int* idx4   = (int*)p;              p += 3456 * 4;
    int* offs   = (int*)p;              p += 256;
    int* rows_tv= (int*)p;              p += 3456 * 4;
    int* rows_s = (int*)p;              p += 3456 * 4;
    unsigned short* wbf = (unsigned short*)p;  // 16*2048*512 ushorts = 33.6 MB (reused)
    // transformer transposed weights live inside wbf after MoE is done:
    unsigned short* qkvwt = wbf;                           // 3*1536*512
    unsigned short* aowt  = qkvwt + 3 * 1536 * 512;        // 3*512*512
    unsigned short* fw1t  = aowt  + 3 * 512 * 512;         // 3*2048*512
    unsigned short* fw2t  = fw1t  + 3 * 2048 * 512;        // 3*512*2048

    build_tokens<<<dim3(NTV), dim3(256), 0, stream>>>(
        Z, emb0, p0w, p0b, emb1, p1w, p1b, emb2, p2w, p2b,
        keys, rw, rb, v, w4, idx4);
    route_kernel<<<dim3(1), dim3(256), 0, stream>>>(idx4, offs, rows_tv, rows_s);

    // MoE phase 1
    transpose_to_bf16<<<dim3(2048 / 64, 512 / 64, 16), dim3(256), 0, stream>>>(ew1, wbf, 512, 2048);
    gemm_moe_mfma<<<dim3(2048 / 64, NEXP, 14), dim3(256), 0, stream>>>(
        v, nullptr, rows_tv, rows_s, offs, wbf, eb1, h, nullptr, HFF, DMODEL, 1);
    // MoE phase 2 (reuse wbf)
    transpose_to_bf16<<<dim3(512 / 64, 2048 / 64, 16), dim3(256), 0, stream>>>(ew2, wbf, 2048, 512);
    gemm_moe_mfma<<<dim3(512 / 64, NEXP, 14), dim3(256), 0, stream>>>(
        nullptr, h, rows_tv, rows_s, offs, wbf, eb2, nullptr, yall, DMODEL, HFF, 2);

    fuse_kernel<<<dim3(NTOK), dim3(256), 0, stream>>>(yall, w4, frac, xbuf);

    // transformer weights (reuse wbf region after MoE)
    transpose_to_bf16<<<dim3(1536 / 64, 512 / 64, 3), dim3(256), 0, stream>>>(qkv_w, qkvwt, 512, 1536);
    transpose_to_bf16<<<dim3(512 / 64, 512 / 64, 3), dim3(256), 0, stream>>>(aow, aowt, 512, 512);
    transpose_to_bf16<<<dim3(2048 / 64, 512 / 64, 3), dim3(256), 0, stream>>>(fw1, fw1t, 512, 2048);
    transpose_to_bf16<<<dim3(512 / 64, 2048 / 64, 3), dim3(256), 0, stream>>>(fw2, fw2t, 2048, 512);

    for (int i = 0; i < 3; ++i) {
        gemm_dense_mfma<<<dim3(1536 / 64, 5), dim3(256), 0, stream>>>(
            xbuf, qkvwt + (size_t)i * 1536 * 512, qkv_b + i * 1536, qkvb, NTOK, 1536, 512, 0);
        attn_kernel<<<dim3(256), dim3(64), 0, stream>>>(qkvb, obuf);
        gemm_dense_mfma<<<dim3(512 / 64, 5), dim3(256), 0, stream>>>(
            obuf, aowt + (size_t)i * 512 * 512, aob + i * 512, tmp, NTOK, 512, 512, 0);
        ln_kernel<<<dim3(NTOK), dim3(256), 0, stream>>>(xbuf, tmp, ln1g + i * 512, ln1b + i * 512);
        gemm_dense_mfma<<<dim3(2048 / 64, 5), dim3(256), 0, stream>>>(
            xbuf, fw1t + (size_t)i * 2048 * 512, fb1 + i * 2048, f1, NTOK, 2048, 512, 1);
        gemm_dense_mfma<<<dim3(512 / 64, 5), dim3(256), 0, stream>>>(
            f1, fw2t + (size_t)i * 512 * 2048, fb2 + i * 512, tmp, NTOK, 512, 2048, 0);
        ln_kernel<<<dim3(NTOK), dim3(256), 0, stream>>>(xbuf, tmp, ln2g + i * 512, ln2b + i * 512);
    }

    finalize_kernel<<<dim3(NTOK * DMODEL / 256), dim3(256), 0, stream>>>(xbuf, frac, out);
}

// Round 3
// 581.009 us; speedup vs baseline: 3.3564x; 1.1604x over previous
//
#include <hip/hip_runtime.h>
#include <hip/hip_bf16.h>
#include <math.h>

#define NTOK   288      // B*L
#define NV     3
#define NTV    864      // NV*NTOK
#define NSEL   3456     // NTV*4
#define DMODEL 512
#define NEXP   16
#define TOPK   4
#define HFF    2048
#define RESN   5000

typedef short v8s __attribute__((ext_vector_type(8)));
typedef float v4f __attribute__((ext_vector_type(4)));
typedef unsigned short ushort_t;

__device__ __forceinline__ float gelu_exact(float x) {
    return 0.5f * x * (1.0f + erff(x * 0.70710678118654752f));
}
__device__ __forceinline__ unsigned f2bf1(float f) {
    unsigned u = __builtin_bit_cast(unsigned, f);
    return (u + 0x7fffu + ((u >> 16) & 1u)) >> 16;
}
__device__ __forceinline__ unsigned pack2(float a, float b) {
    return f2bf1(a) | (f2bf1(b) << 16);
}
__device__ __forceinline__ float bf2f(ushort_t u) {
    return __builtin_bit_cast(float, (unsigned)u << 16);
}

// ---------------- K0: views + router + top-k (writes v in bf16) ----------------
__global__ __launch_bounds__(256) void build_tokens(
    const int* __restrict__ Z,
    const float* __restrict__ emb0, const float* __restrict__ p0w, const float* __restrict__ p0b,
    const float* __restrict__ emb1, const float* __restrict__ p1w, const float* __restrict__ p1b,
    const float* __restrict__ emb2, const float* __restrict__ p2w, const float* __restrict__ p2b,
    const float* __restrict__ keys, const float* __restrict__ router_w, const float* __restrict__ router_b,
    ushort_t* __restrict__ vbf, float* __restrict__ w4, int* __restrict__ idx4)
{
    int tv = blockIdx.x;
    int vi = tv / NTOK, t = tv % NTOK;
    int tid = threadIdx.x;

    const float* emb; const float* pw; const float* pb; int F;
    if (vi == 0)      { emb = emb0; pw = p0w; pb = p0b; F = 200; }
    else if (vi == 1) { emb = emb1; pw = p1w; pb = p1b; F = 132; }
    else              { emb = emb2; pw = p2w; pb = p2b; F = 112; }
    const float* rw = router_w + (size_t)vi * DMODEL * NEXP;
    const float* rb = router_b + vi * NEXP;

    __shared__ float er[200];
    __shared__ float vs[DMODEL];
    __shared__ float red[256];
    __shared__ float logits[NEXP];
    __shared__ float vsq_s;

    int z = Z[t];
    for (int f = tid; f < F; f += 256) er[f] = emb[(size_t)z * F + f];
    __syncthreads();

    float a0 = pb[tid], a1 = pb[tid + 256];
    for (int f = 0; f < F; ++f) {
        float e = er[f];
        a0 += e * pw[f * DMODEL + tid];
        a1 += e * pw[f * DMODEL + tid + 256];
    }
    vs[tid] = a0; vs[tid + 256] = a1;
    vbf[(size_t)tv * DMODEL + tid]       = (ushort_t)f2bf1(a0);
    vbf[(size_t)tv * DMODEL + tid + 256] = (ushort_t)f2bf1(a1);

    red[tid] = a0 * a0 + a1 * a1;
    __syncthreads();
    for (int s = 128; s > 0; s >>= 1) { if (tid < s) red[tid] += red[tid + s]; __syncthreads(); }
    if (tid == 0) vsq_s = red[0];
    __syncthreads();
    float vsq = vsq_s;

    int lane = tid & 63, wv = tid >> 6;
    for (int ei = 0; ei < 4; ++ei) {
        int e = wv * 4 + ei;
        float p = 0.0f;
        for (int d = lane; d < DMODEL; d += 64) {
            float vvv = vs[d];
            float kk = keys[e * DMODEL + d];
            p += vvv * rw[d * NEXP + e] - kk * (kk - 2.0f * vvv);
        }
        for (int off = 32; off > 0; off >>= 1) p += __shfl_down(p, off, 64);
        if (lane == 0) logits[e] = -vsq + p + rb[e];
    }
    __syncthreads();

    if (tid == 0) {
        float lv[NEXP];
        for (int e = 0; e < NEXP; ++e) lv[e] = logits[e];
        bool used[NEXP] = {false};
        int   tk[TOPK]; float tval[TOPK];
        for (int k = 0; k < TOPK; ++k) {
            int best = -1; float bv = -1e30f;
            for (int e = 0; e < NEXP; ++e)
                if (!used[e] && lv[e] > bv) { bv = lv[e]; best = e; }
            used[best] = true; tk[k] = best; tval[k] = bv;
        }
        float m = tval[0], sum = 0.0f, ww[TOPK];
        for (int k = 0; k < TOPK; ++k) { ww[k] = expf(tval[k] - m); sum += ww[k]; }
        for (int k = 0; k < TOPK; ++k) {
            w4[tv * TOPK + k] = ww[k] / sum;
            idx4[tv * TOPK + k] = tk[k];
        }
    }
}

// ---------------- K1: compact rows per expert ----------------
__global__ __launch_bounds__(256) void route_kernel(
    const int* __restrict__ idx4, int* __restrict__ offs,
    int* __restrict__ rows_tv, int* __restrict__ rows_s)
{
    __shared__ int cnt[NEXP], cur[NEXP], offsh[NEXP + 1];
    int tid = threadIdx.x;
    if (tid < NEXP) cnt[tid] = 0;
    __syncthreads();
    for (int s = tid; s < NSEL; s += 256) atomicAdd(&cnt[idx4[s]], 1);
    __syncthreads();
    if (tid == 0) {
        int o = 0;
        for (int e = 0; e < NEXP; ++e) { offsh[e] = o; o += cnt[e]; }
        offsh[NEXP] = o;
    }
    __syncthreads();
    if (tid < NEXP) cur[tid] = offsh[tid];
    if (tid <= NEXP) offs[tid] = offsh[tid];
    __syncthreads();
    for (int s = tid; s < NSEL; s += 256) {
        int e = idx4[s];
        int pos = atomicAdd(&cur[e], 1);
        rows_tv[pos] = s >> 2;
        rows_s[pos]  = s;
    }
}

// ---------------- transpose tile helper: [K][N] -> [N][K] bf16 ----------------
__device__ __forceinline__ void tile_transpose(
    const float* __restrict__ src_b, ushort_t* __restrict__ out_b,
    int K, int N, int k0, int n0, int tid)
{
    __shared__ ushort_t T[64 * 72];
    int r = tid >> 2, c = tid & 3;
    const float* src = src_b + (size_t)(k0 + r) * N + n0 + c * 16;
    float4 f0 = *(const float4*)(src + 0);
    float4 f1 = *(const float4*)(src + 4);
    float4 f2 = *(const float4*)(src + 8);
    float4 f3 = *(const float4*)(src + 12);
    uint4 u0, u1;
    u0.x = pack2(f0.x, f0.y); u0.y = pack2(f0.z, f0.w);
    u0.z = pack2(f1.x, f1.y); u0.w = pack2(f1.z, f1.w);
    u1.x = pack2(f2.x, f2.y); u1.y = pack2(f2.z, f2.w);
    u1.z = pack2(f3.x, f3.y); u1.w = pack2(f3.z, f3.w);
    *(uint4*)&T[r * 72 + c * 16]     = u0;
    *(uint4*)&T[r * 72 + c * 16 + 8] = u1;
    __syncthreads();
    uint4 o0, o1;
#pragma unroll
    for (int j = 0; j < 16; j += 2) {
        unsigned lo = T[(c * 16 + j)     * 72 + r];
        unsigned hi = T[(c * 16 + j + 1) * 72 + r];
        if (j < 8) ((unsigned*)&o0)[j >> 1] = lo | (hi << 16);
        else       ((unsigned*)&o1)[(j - 8) >> 1] = lo | (hi << 16);
    }
    ushort_t* dst = out_b + (size_t)(n0 + r) * K + k0 + c * 16;
    *(uint4*)(dst)     = o0;
    *(uint4*)(dst + 8) = o1;
}

__global__ __launch_bounds__(256) void transpose_to_bf16(
    const float* __restrict__ in, ushort_t* __restrict__ out, int K, int N)
{
    size_t boff = (size_t)blockIdx.z * (size_t)K * N;
    tile_transpose(in + boff, out + boff, K, N, blockIdx.y * 64, blockIdx.x * 64, threadIdx.x);
}

// one dispatch for all transformer weights
__global__ __launch_bounds__(256) void transpose_jobs(
    const float* __restrict__ qkvw, const float* __restrict__ aow,
    const float* __restrict__ fw1,  const float* __restrict__ fw2,
    ushort_t* __restrict__ qkvwt, ushort_t* __restrict__ aowt,
    ushort_t* __restrict__ fw1t,  ushort_t* __restrict__ fw2t)
{
    int b = blockIdx.x;
    const float* src; ushort_t* dst; int K, N, nt;
    if (b < 576)       { b -= 0;    src = qkvw; dst = qkvwt; K = 512;  N = 1536; nt = 24; }
    else if (b < 768)  { b -= 576;  src = aow;  dst = aowt;  K = 512;  N = 512;  nt = 8;  }
    else if (b < 1536) { b -= 768;  src = fw1;  dst = fw1t;  K = 512;  N = 2048; nt = 32; }
    else               { b -= 1536; src = fw2;  dst = fw2t;  K = 2048; N = 512;  nt = 8;  }
    int per = nt * (K / 64);
    int z = b / per, r = b % per;
    int n0 = (r % nt) * 64, k0 = (r / nt) * 64;
    size_t boff = (size_t)z * (size_t)K * N;
    tile_transpose(src + boff, dst + boff, K, N, k0, n0, threadIdx.x);
}

// ---------------- MoE phase 1: h = gelu(v @ ew1 + b1), W read once ----------------
// grid (2048/64, 16), block 256
__global__ __launch_bounds__(256) void moe_gemm1(
    const ushort_t* __restrict__ vbf, const int* __restrict__ rows_tv,
    const int* __restrict__ offs, const ushort_t* __restrict__ wt,
    const float* __restrict__ eb1, ushort_t* __restrict__ h)
{
    int e = blockIdx.y;
    int off = offs[e], cnt = offs[e + 1] - off;
    int n0 = blockIdx.x * 64;
    const ushort_t* wte = wt + (size_t)e * HFF * DMODEL;
    const float* bias = eb1 + (size_t)e * HFF;
    __shared__ ushort_t Bs[64 * 64];
    int tid = threadIdx.x, w = tid >> 6, lane = tid & 63, lm = lane & 15, lq = lane >> 4;
    int srow = tid >> 2, sk = (tid & 3) * 16;
    const ushort_t* wrow = wte + (size_t)(n0 + srow) * DMODEL + sk;

    for (int mt = 0; mt < cnt; mt += 256) {
        const ushort_t* arow[4];
#pragma unroll
        for (int mf = 0; mf < 4; ++mf) {
            int r = mt + w * 64 + mf * 16 + lm;
            r = min(r, cnt - 1);
            arow[mf] = vbf + (size_t)rows_tv[off + r] * DMODEL;
        }
        v4f acc[4][4];
#pragma unroll
        for (int a = 0; a < 4; ++a)
#pragma unroll
            for (int b = 0; b < 4; ++b) acc[a][b] = (v4f){0.f, 0.f, 0.f, 0.f};

        for (int kp = 0; kp < DMODEL; kp += 64) {
            *(uint4*)&Bs[srow * 64 + sk]     = *(const uint4*)(wrow + kp);
            *(uint4*)&Bs[srow * 64 + sk + 8] = *(const uint4*)(wrow + kp + 8);
            __syncthreads();
#pragma unroll
            for (int s = 0; s < 64; s += 32) {
                v8s a[4];
#pragma unroll
                for (int mf = 0; mf < 4; ++mf)
                    a[mf] = *(const v8s*)(arow[mf] + kp + s + lq * 8);
#pragma unroll
                for (int nt = 0; nt < 4; ++nt) {
                    v8s bfr = *(const v8s*)&Bs[(nt * 16 + lm) * 64 + s + lq * 8];
#pragma unroll
                    for (int mf = 0; mf < 4; ++mf)
                        acc[mf][nt] = __builtin_amdgcn_mfma_f32_16x16x32_bf16(a[mf], bfr, acc[mf][nt], 0, 0, 0);
                }
            }
            __syncthreads();
        }
#pragma unroll
        for (int mf = 0; mf < 4; ++mf)
#pragma unroll
            for (int nt = 0; nt < 4; ++nt) {
                int col = n0 + nt * 16 + lm;
                float bv = bias[col];
#pragma unroll
                for (int i = 0; i < 4; ++i) {
                    int r = mt + w * 64 + mf * 16 + lq * 4 + i;
                    if (r < cnt) {
                        float val = gelu_exact(acc[mf][nt][i] + bv);
                        h[(size_t)(off + r) * HFF + col] = (ushort_t)f2bf1(val);
                    }
                }
            }
    }
}

// ---------------- MoE phase 2: yall[z] = h @ ew2 (K-split), W read once ----------------
// grid (512/64, 16, 2), block 256
__global__ __launch_bounds__(256) void moe_gemm2(
    const ushort_t* __restrict__ h, const int* __restrict__ rows_s,
    const int* __restrict__ offs, const ushort_t* __restrict__ wt,
    const float* __restrict__ eb2, float* __restrict__ yall)
{
    int e = blockIdx.y;
    int off = offs[e], cnt = offs[e + 1] - off;
    int n0 = blockIdx.x * 64;
    int z = blockIdx.z;
    int kp0 = z * (HFF / 2);
    const ushort_t* wte = wt + (size_t)e * DMODEL * HFF;
    const float* bias = eb2 + (size_t)e * DMODEL;
    float* yz = yall + (size_t)z * NSEL * DMODEL;
    __shared__ ushort_t Bs[64 * 64];
    int tid = threadIdx.x, w = tid >> 6, lane = tid & 63, lm = lane & 15, lq = lane >> 4;
    int srow = tid >> 2, sk = (tid & 3) * 16;
    const ushort_t* wrow = wte + (size_t)(n0 + srow) * HFF + kp0 + sk;

    for (int mt = 0; mt < cnt; mt += 256) {
        const ushort_t* arow[4];
#pragma unroll
        for (int mf = 0; mf < 4; ++mf) {
            int r = mt + w * 64 + mf * 16 + lm;
            r = min(r, cnt - 1);
            arow[mf] = h + (size_t)(off + r) * HFF + kp0;
        }
        v4f acc[4][4];
#pragma unroll
        for (int a = 0; a < 4; ++a)
#pragma unroll
            for (int b = 0; b < 4; ++b) acc[a][b] = (v4f){0.f, 0.f, 0.f, 0.f};

        for (int kp = 0; kp < HFF / 2; kp += 64) {
            *(uint4*)&Bs[srow * 64 + sk]     = *(const uint4*)(wrow + kp);
            *(uint4*)&Bs[srow * 64 + sk + 8] = *(const uint4*)(wrow + kp + 8);
            __syncthreads();
#pragma unroll
            for (int s = 0; s < 64; s += 32) {
                v8s a[4];
#pragma unroll
                for (int mf = 0; mf < 4; ++mf)
                    a[mf] = *(const v8s*)(arow[mf] + kp + s + lq * 8);
#pragma unroll
                for (int nt = 0; nt < 4; ++nt) {
                    v8s bfr = *(const v8s*)&Bs[(nt * 16 + lm) * 64 + s + lq * 8];
#pragma unroll
                    for (int mf = 0; mf < 4; ++mf)
                        acc[mf][nt] = __builtin_amdgcn_mfma_f32_16x16x32_bf16(a[mf], bfr, acc[mf][nt], 0, 0, 0);
                }
            }
            __syncthreads();
        }
#pragma unroll
        for (int mf = 0; mf < 4; ++mf)
#pragma unroll
            for (int nt = 0; nt < 4; ++nt) {
                int col = n0 + nt * 16 + lm;
                float bv = (z == 0) ? bias[col] : 0.0f;
#pragma unroll
                for (int i = 0; i < 4; ++i) {
                    int r = mt + w * 64 + mf * 16 + lq * 4 + i;
                    if (r < cnt) {
                        int sidx = rows_s[off + r];
                        yz[(size_t)sidx * DMODEL + col] = acc[mf][nt][i] + bv;
                    }
                }
            }
    }
}

// ---------------- dense GEMM: bf16 A [M][K], Wt [N][K], K-split, modes ----------------
// mode 0: fp32 out to Cout + z*M*N (partials)   mode 1: relu -> bf16   mode 2: bf16
__global__ __launch_bounds__(256) void gemm_dense2(
    const ushort_t* __restrict__ A, const ushort_t* __restrict__ Wt,
    const float* __restrict__ bias, void* __restrict__ Cout,
    int M, int N, int K, int Kslice, int mode)
{
    int n0 = blockIdx.x * 64, m0 = blockIdx.y * 64, z = blockIdx.z;
    int kp0 = z * Kslice;
    __shared__ ushort_t Bs[64 * 64];
    int tid = threadIdx.x, w = tid >> 6, lane = tid & 63, lm = lane & 15, lq = lane >> 4;
    int srow = tid >> 2, sk = (tid & 3) * 16;
    const ushort_t* wrow = Wt + (size_t)(n0 + srow) * K + kp0 + sk;
    int m = min(m0 + w * 16 + lm, M - 1);
    const ushort_t* arow = A + (size_t)m * K + kp0;

    v4f acc[4];
#pragma unroll
    for (int nt = 0; nt < 4; ++nt) acc[nt] = (v4f){0.f, 0.f, 0.f, 0.f};

    for (int kp = 0; kp < Kslice; kp += 64) {
        *(uint4*)&Bs[srow * 64 + sk]     = *(const uint4*)(wrow + kp);
        *(uint4*)&Bs[srow * 64 + sk + 8] = *(const uint4*)(wrow + kp + 8);
        __syncthreads();
#pragma unroll
        for (int s = 0; s < 64; s += 32) {
            v8s a = *(const v8s*)(arow + kp + s + lq * 8);
#pragma unroll
            for (int nt = 0; nt < 4; ++nt) {
                v8s bfr = *(const v8s*)&Bs[(nt * 16 + lm) * 64 + s + lq * 8];
                acc[nt] = __builtin_amdgcn_mfma_f32_16x16x32_bf16(a, bfr, acc[nt], 0, 0, 0);
            }
        }
        __syncthreads();
    }
#pragma unroll
    for (int nt = 0; nt < 4; ++nt) {
        int col = n0 + nt * 16 + lm;
        float bv = (z == 0) ? bias[col] : 0.0f;
#pragma unroll
        for (int i = 0; i < 4; ++i) {
            int row = m0 + w * 16 + lq * 4 + i;
            if (row < M) {
                float val = acc[nt][i] + bv;
                if (mode == 0) {
                    ((float*)Cout)[(size_t)z * M * N + (size_t)row * N + col] = val;
                } else if (mode == 1) {
                    val = fmaxf(val, 0.f);
                    ((ushort_t*)Cout)[(size_t)row * N + col] = (ushort_t)f2bf1(val);
                } else {
                    ((ushort_t*)Cout)[(size_t)row * N + col] = (ushort_t)f2bf1(val);
                }
            }
        }
    }
}

// ---------------- fuse: weighted MoE gather (2 K-split partials) + PE ----------------
__global__ __launch_bounds__(256) void fuse_kernel(
    const float* __restrict__ y_all, const float* __restrict__ w4,
    const float* __restrict__ frac, float* __restrict__ x, ushort_t* __restrict__ xbf)
{
    int t = blockIdx.x;
    int tid = threadIdx.x;
    __shared__ float wsh[12];
    __shared__ int idxsh[2];
    if (tid < 12) {
        int vi = tid >> 2, kk = tid & 3;
        wsh[tid] = w4[((size_t)vi * NTOK + t) * TOPK + kk];
    }
    if (tid == 0) {
        double r = (double)frac[t];
        double rl = fmax(r, 1.0 / RESN);
        int il = (int)rint(rl * RESN) - 1;
        idxsh[0] = min(max(il, 0), RESN - 1);
        double lg = log2(r);
        double rg = 0.0025 * lg * lg;
        rg = fmin(rg, 1.0);
        rg = fmax(rg, 1.0 / RESN);
        int ig = (int)rint(rg * RESN) - 1;
        idxsh[1] = min(max(ig, 0), RESN - 1);
    }
    __syncthreads();
    for (int d = tid; d < DMODEL; d += 256) {
        float acc = 0.0f;
        for (int c = 0; c < 12; ++c) {
            int vi = c >> 2, kk = c & 3;
            size_t s = ((size_t)vi * NTOK + t) * TOPK + kk;
            float y = y_all[s * DMODEL + d] + y_all[(size_t)NSEL * DMODEL + s * DMODEL + d];
            acc += wsh[c] * y;
        }
        int cc  = (d < 256) ? d : d - 256;
        int idx = (d < 256) ? idxsh[0] : idxsh[1];
        double arg = (double)idx / pow(50.0, 2.0 * (double)cc / 256.0);
        double pe = (cc & 1) ? cos(arg) : sin(arg);
        float val = acc + (float)pe;
        x[(size_t)t * DMODEL + d] = val;
        xbf[(size_t)t * DMODEL + d] = (ushort_t)f2bf1(val);
    }
}

// ---------------- attention (bf16 in/out) ----------------
__global__ __launch_bounds__(64) void attn_kernel(
    const ushort_t* __restrict__ qkv, ushort_t* __restrict__ o)
{
    int bh = blockIdx.x;
    int b = bh >> 3, hh = bh & 7;
    int t0 = b * 9;
    __shared__ float q[9][64], k[9][64], v[9][64], sc[81], p[9][9];
    int t = threadIdx.x;
    for (int i = 0; i < 9; ++i) {
        const ushort_t* row = qkv + (size_t)(t0 + i) * 1536 + hh * 64 + t;
        q[i][t] = bf2f(row[0]); k[i][t] = bf2f(row[512]); v[i][t] = bf2f(row[1024]);
    }
    __syncthreads();
    for (int ij = t; ij < 81; ij += 64) {
        int i = ij / 9, j = ij % 9;
        float s = 0.0f;
        for (int d = 0; d < 64; ++d) s += q[i][d] * k[j][d];
        sc[ij] = s * 0.125f;
    }
    __syncthreads();
    if (t < 9) {
        float m = -1e30f;
        for (int j = 0; j < 9; ++j) m = fmaxf(m, sc[t * 9 + j]);
        float sum = 0.0f, e[9];
        for (int j = 0; j < 9; ++j) { e[j] = expf(sc[t * 9 + j] - m); sum += e[j]; }
        for (int j = 0; j < 9; ++j) p[t][j] = e[j] / sum;
    }
    __syncthreads();
    for (int i = 0; i < 9; ++i) {
        float acc = 0.0f;
        for (int j = 0; j < 9; ++j) acc += p[i][j] * v[j][t];
        o[(size_t)(t0 + i) * DMODEL + hh * 64 + t] = (ushort_t)f2bf1(acc);
    }
}

// ---------------- residual(sum of nz partials) + layernorm (+optional final) ----------------
__global__ __launch_bounds__(256) void ln_kernel(
    float* __restrict__ x, ushort_t* __restrict__ xbf,
    const float* __restrict__ tmp, int nz,
    const float* __restrict__ g, const float* __restrict__ b,
    float* __restrict__ out, const float* __restrict__ frac)
{
    int t = blockIdx.x;
    int tid = threadIdx.x;
    __shared__ float red[256];
    __shared__ float stat;
    size_t base = (size_t)t * DMODEL;
    float r0 = 0.f, r1 = 0.f;
    for (int z = 0; z < nz; ++z) {
        r0 += tmp[(size_t)z * NTOK * DMODEL + base + tid];
        r1 += tmp[(size_t)z * NTOK * DMODEL + base + 256 + tid];
    }
    float v0 = x[base + tid] + r0;
    float v1 = x[base + 256 + tid] + r1;
    red[tid] = v0 + v1;
    __syncthreads();
    for (int s = 128; s > 0; s >>= 1) { if (tid < s) red[tid] += red[tid + s]; __syncthreads(); }
    if (tid == 0) stat = red[0] * (1.0f / DMODEL);
    __syncthreads();
    float m = stat;
    float d0 = v0 - m, d1 = v1 - m;
    red[tid] = d0 * d0 + d1 * d1;
    __syncthreads();
    for (int s = 128; s > 0; s >>= 1) { if (tid < s) red[tid] += red[tid + s]; __syncthreads(); }
    if (tid == 0) stat = rsqrtf(red[0] * (1.0f / DMODEL) + 1e-5f);
    __syncthreads();
    float is = stat;
    float o0 = d0 * is * g[tid] + b[tid];
    float o1 = d1 * is * g[256 + tid] + b[256 + tid];
    x[base + tid]       = o0;
    x[base + 256 + tid] = o1;
    xbf[base + tid]       = (ushort_t)f2bf1(o0);
    xbf[base + 256 + tid] = (ushort_t)f2bf1(o1);
    if (out) {
        float fr = frac[t];
        out[base + tid]       = o0 * fr;
        out[base + 256 + tid] = o1 * fr;
    }
}

extern "C" void kernel_launch(void* const* d_in, const int* in_sizes, int n_in,
                              void* d_out, int out_size, void* d_ws, size_t ws_size,
                              hipStream_t stream) {
    const int*   Z      = (const int*)d_in[0];
    const float* frac   = (const float*)d_in[1];
    const float* emb0   = (const float*)d_in[2];
    const float* p0w    = (const float*)d_in[3];
    const float* p0b    = (const float*)d_in[4];
    const float* emb1   = (const float*)d_in[5];
    const float* p1w    = (const float*)d_in[6];
    const float* p1b    = (const float*)d_in[7];
    const float* emb2   = (const float*)d_in[8];
    const float* p2w    = (const float*)d_in[9];
    const float* p2b    = (const float*)d_in[10];
    const float* keys   = (const float*)d_in[11];
    const float* rw     = (const float*)d_in[12];
    const float* rb     = (const float*)d_in[13];
    const float* ew1    = (const float*)d_in[14];
    const float* eb1    = (const float*)d_in[15];
    const float* ew2    = (const float*)d_in[16];
    const float* eb2    = (const float*)d_in[17];
    const float* qkv_w  = (const float*)d_in[18];
    const float* qkv_b  = (const float*)d_in[19];
    const float* aow    = (const float*)d_in[20];
    const float* aob    = (const float*)d_in[21];
    const float* ln1g   = (const float*)d_in[22];
    const float* ln1b   = (const float*)d_in[23];
    const float* ln2g   = (const float*)d_in[24];
    const float* ln2b   = (const float*)d_in[25];
    const float* fw1    = (const float*)d_in[26];
    const float* fb1    = (const float*)d_in[27];
    const float* fw2    = (const float*)d_in[28];
    const float* fb2    = (const float*)d_in[29];
    float* out = (float*)d_out;

    // workspace layout
    char* p = (char*)d_ws;
    // union region U: phase A = vbf|h|yall0|yall1 ; phase B (after fuse) = transformer Wt
    char* U = p;
    ushort_t* vbf   = (ushort_t*)U;                               // 864*512*2       = 884736
    ushort_t* h     = (ushort_t*)(U + 884736);                    // 3456*2048*2     = 14155776
    float*    yall  = (float*)(U + 884736 + 14155776);            // 2*3456*512*4    = 14155776
    ushort_t* qkvwt = (ushort_t*)U;                               // 3*1536*512*2 = 4718592
    ushort_t* aowt  = qkvwt + 3 * 1536 * 512;                     // 3*512*512*2  = 1572864
    ushort_t* fw1t  = aowt  + 3 * 512 * 512;                      // 3*2048*512*2 = 6291456
    ushort_t* fw2t  = fw1t  + 3 * 2048 * 512;                     // 3*512*2048*2 = 6291456
    p = U + 884736 + 14155776 + 14155776;                         // = 29196288
    float* xbuf = (float*)p;            p += 288 * 512 * 4;
    ushort_t* xbf = (ushort_t*)p;       p += 288 * 512 * 2;
    ushort_t* qkvb = (ushort_t*)p;      p += 288 * 1536 * 2;
    ushort_t* obf = (ushort_t*)p;       p += 288 * 512 * 2;
    float* tmp  = (float*)p;            p += 4 * 288 * 512 * 4;   // up to 4 partial slices
    ushort_t* f1b = (ushort_t*)p;       p += 288 * 2048 * 2;
    float* w4   = (float*)p;            p += 3456 * 4;
    int* idx4   = (int*)p;              p += 3456 * 4;
    int* offs   = (int*)p;              p += 256;
    int* rows_tv= (int*)p;              p += 3456 * 4;
    int* rows_s = (int*)p;              p += 3456 * 4;
    ushort_t* wt = (ushort_t*)p;        // 16*2048*512*2 = 33.6 MB (ew1t then ew2t)

    build_tokens<<<dim3(NTV), dim3(256), 0, stream>>>(
        Z, emb0, p0w, p0b, emb1, p1w, p1b, emb2, p2w, p2b,
        keys, rw, rb, vbf, w4, idx4);
    route_kernel<<<dim3(1), dim3(256), 0, stream>>>(idx4, offs, rows_tv, rows_s);

    // MoE phase 1
    transpose_to_bf16<<<dim3(2048 / 64, 512 / 64, 16), dim3(256), 0, stream>>>(ew1, wt, 512, 2048);
    moe_gemm1<<<dim3(2048 / 64, NEXP), dim3(256), 0, stream>>>(vbf, rows_tv, offs, wt, eb1, h);
    // MoE phase 2 (reuse wt)
    transpose_to_bf16<<<dim3(512 / 64, 2048 / 64, 16), dim3(256), 0, stream>>>(ew2, wt, 2048, 512);
    moe_gemm2<<<dim3(512 / 64, NEXP, 2), dim3(256), 0, stream>>>(h, rows_s, offs, wt, eb2, yall);

    fuse_kernel<<<dim3(NTOK), dim3(256), 0, stream>>>(yall, w4, frac, xbuf, xbf);

    // transformer weights (overwrite U region — vbf/h/yall dead after fuse)
    transpose_jobs<<<dim3(2304), dim3(256), 0, stream>>>(
        qkv_w, aow, fw1, fw2, qkvwt, aowt, fw1t, fw2t);

    for (int i = 0; i < 3; ++i) {
        gemm_dense2<<<dim3(24, 5, 1), dim3(256), 0, stream>>>(
            xbf, qkvwt + (size_t)i * 1536 * 512, qkv_b + i * 1536, qkvb, NTOK, 1536, 512, 512, 2);
        attn_kernel<<<dim3(256), dim3(64), 0, stream>>>(qkvb, obf);
        gemm_dense2<<<dim3(8, 5, 2), dim3(256), 0, stream>>>(
            obf, aowt + (size_t)i * 512 * 512, aob + i * 512, tmp, NTOK, 512, 512, 256, 0);
        ln_kernel<<<dim3(NTOK), dim3(256), 0, stream>>>(
            xbuf, xbf, tmp, 2, ln1g + i * 512, ln1b + i * 512, nullptr, nullptr);
        gemm_dense2<<<dim3(32, 5, 1), dim3(256), 0, stream>>>(
            xbf, fw1t + (size_t)i * 2048 * 512, fb1 + i * 2048, f1b, NTOK, 2048, 512, 512, 1);
        gemm_dense2<<<dim3(8, 5, 4), dim3(256), 0, stream>>>(
            f1b, fw2t + (size_t)i * 512 * 2048, fb2 + i * 512, tmp, NTOK, 512, 2048, 512, 0);
        ln_kernel<<<dim3(NTOK), dim3(256), 0, stream>>>(
            xbuf, xbf, tmp, 4, ln2g + i * 512, ln2b + i * 512,
            (i == 2) ? out : nullptr, frac);
    }
}